// Round 2
// baseline (129.127 us; speedup 1.0000x reference)
//
#include <hip/hip_runtime.h>

#define BETA_F 0.9f

__device__ __forceinline__ float fsigmoid(float x) {
    float e = __expf(-x);
    return __builtin_amdgcn_rcpf(1.0f + e);
}

// ---------------- Kernel 1: bilin = P @ W ----------------
// grid 1024: each block computes 8 rows x 128 cols. block 256.
__global__ __launch_bounds__(256, 8) void bilin_kernel(
    const float* __restrict__ pin,   // [8192][128]
    const float* __restrict__ W,     // [128][128]
    float* __restrict__ gout)        // [8192][128]
{
    __shared__ float A[8][132];
    const int t  = threadIdx.x;
    const int r0 = blockIdx.x * 8;

    // stage 8 rows (256 float4, one per thread)
    {
        int row = t >> 5, col = (t & 31) << 2;
        float4 v = *(const float4*)(pin + (size_t)(r0 + row) * 128 + col);
        *(float4*)&A[row][col] = v;
    }
    __syncthreads();

    const int k  = t >> 5;          // local row 0..7
    const int eg = (t & 31) << 2;   // e base
    float4 acc = make_float4(0.f, 0.f, 0.f, 0.f);
    for (int d = 0; d < 128; d += 4) {
        float4 a = *(const float4*)&A[k][d];
        float ar[4] = {a.x, a.y, a.z, a.w};
        #pragma unroll
        for (int dd = 0; dd < 4; ++dd) {
            float4 w = *(const float4*)(W + (size_t)(d + dd) * 128 + eg);
            acc.x += ar[dd] * w.x; acc.y += ar[dd] * w.y;
            acc.z += ar[dd] * w.z; acc.w += ar[dd] * w.w;
        }
    }
    *(float4*)(gout + (size_t)(r0 + k) * 128 + eg) = acc;
}

// ---------------- Kernel 2: walk ----------------
// grid 1024: blk = bi*4 + jgroup. block 256 = 8 j * 32 lanes; lane owns e = 4g..4g+3.
__global__ __launch_bounds__(256, 8) void walk_kernel(
    const float* __restrict__ pin,   // [8192][128]
    const float* __restrict__ gbuf,  // [8192][128] = bilin
    float* __restrict__ pout)        // [8192][128]
{
    __shared__ float G[32][132];
    const int blk = blockIdx.x;
    const int bi  = blk >> 2;        // 0..255 = b*32 + i
    const int jg  = blk & 3;
    const int b   = bi >> 5;
    const int i   = bi & 31;
    const int t   = threadIdx.x;

    // stage G rows of (b,i): 1024 float4, 4 per thread
    {
        const float4* src = (const float4*)(gbuf + (size_t)bi * 32 * 128);
        #pragma unroll
        for (int q = 0; q < 4; ++q) {
            int f = t + 256 * q;
            float4 v = src[f];
            int r = f >> 5, c = (f & 31) << 2;
            *(float4*)&G[r][c] = v;
        }
    }
    __syncthreads();

    const int j  = jg * 8 + (t >> 5);
    const int g  = t & 31;
    const int e0 = g << 2;
    const bool selfrow = (i == j);
    const unsigned long long grpmask = 0xFFFFFFFFull << (t & 32);

    float4 sacc = make_float4(0.f, 0.f, 0.f, 0.f);
    int cnt = 0;

    if (!selfrow) {
        #pragma unroll 4
        for (int k = 0; k < 32; ++k) {
            if (k == i || k == j) continue;          // eq_mask -> sigmoid(-inf)=0
            const float4 p  = *(const float4*)(pin + ((size_t)((b * 32 + k) * 32 + j) << 7) + e0);
            const float4 gg = *(const float4*)&G[k][e0];
            float4 m;
            m.x = gg.x * p.x; m.y = gg.y * p.y;
            m.z = gg.z * p.z; m.w = gg.w * p.w;
            // zero_mask: row -inf iff product==0 for ALL 128 e of this (j,k)
            float amax = fmaxf(fmaxf(fabsf(m.x), fabsf(m.y)), fmaxf(fabsf(m.z), fabsf(m.w)));
            unsigned long long bal = __ballot(amax != 0.0f);
            if ((bal & grpmask) == 0ull) continue;
            ++cnt;
            sacc.x += fsigmoid(m.x);
            sacc.y += fsigmoid(m.y);
            sacc.z += fsigmoid(m.z);
            sacc.w += fsigmoid(m.w);
        }
    }

    const float matv = (cnt == 0) ? 1.0f : BETA_F;
    const float om   = 1.0f - matv;
    const size_t orow = ((size_t)(bi * 32 + j) << 7) + e0;
    float4 pr = *(const float4*)(pin + orow);
    float4 o;
    o.x = matv * pr.x + om * sacc.x;
    o.y = matv * pr.y + om * sacc.y;
    o.z = matv * pr.z + om * sacc.z;
    o.w = matv * pr.w + om * sacc.w;
    *(float4*)(pout + orow) = o;
}

extern "C" void kernel_launch(void* const* d_in, const int* in_sizes, int n_in,
                              void* d_out, int out_size, void* d_ws, size_t ws_size,
                              hipStream_t stream) {
    (void)in_sizes; (void)n_in; (void)out_size; (void)ws_size;
    const float* pairs = (const float*)d_in[0];
    const float* W     = (const float*)d_in[1];
    float* gb  = (float*)d_ws;                       // 4 MB bilin buffer
    float* tmp = (float*)((char*)d_ws + (size_t)8192 * 128 * sizeof(float)); // 4 MB iter-1 out
    float* out = (float*)d_out;

    // ITER = 2
    bilin_kernel<<<1024, 256, 0, stream>>>(pairs, W, gb);
    walk_kernel<<<1024, 256, 0, stream>>>(pairs, gb, tmp);
    bilin_kernel<<<1024, 256, 0, stream>>>(tmp, W, gb);
    walk_kernel<<<1024, 256, 0, stream>>>(tmp, gb, out);
}